// Round 3
// baseline (654.128 us; speedup 1.0000x reference)
//
#include <hip/hip_runtime.h>
#include <math.h>
#include <stdint.h>

#define NV 300
#define NA 12
#define ND 4
#define NB 2
#define NC 512
#define NSD 2048
#define NGP 2000
#define ROWLEN 14400  // NV*NA*ND

// ---------------------------------------------------------------- k_setup_all
__global__ void __launch_bounds__(512) k_setup_all(
    const float* __restrict__ pose, float* __restrict__ views_rot_g,
    int* __restrict__ view_inds, float* __restrict__ Rsel, int* __restrict__ mmx) {
  int b = blockIdx.x, tid = threadIdx.x;
  __shared__ float sv[NV][3];
  __shared__ float svr[NV][9];
  __shared__ float R[9];
  __shared__ float gv[NV][3];
  __shared__ float gvr[NV];
  if (b == 0 && tid == 0) { mmx[0] = 0; mmx[1] = 0x7f800000; }  // umax=0, umin=+inf
  if (tid < 9) R[tid] = pose[b * 12 + (tid / 3) * 4 + (tid % 3)];
  if (tid < NV) {
    float fi = (float)tid;
    float Z = (2.0f * fi + 1.0f) / 300.0f - 1.0f;
    float r = sqrtf(fmaxf(1.0f - Z * Z, 0.0f));
    float ang = (6.28318530717958647692f * fi) * 0.61803398874989484820f;
    float X = r * cosf(ang);
    float Y = r * sinf(ang);
    sv[tid][0] = X; sv[tid][1] = Y; sv[tid][2] = Z;
    float ax0 = -X, ax1 = -Y, ax2 = -Z;
    float ay0 = -ax1, ay1 = ax0, ay2 = 0.f;      // from UNNORMALIZED ax
    float ynorm = sqrtf(ay0 * ay0 + ay1 * ay1 + ay2 * ay2);
    if (ynorm == 0.f) { ay0 = 0.f; ay1 = 1.f; ay2 = 0.f; }
    float an = sqrtf(ax0 * ax0 + ax1 * ax1 + ax2 * ax2);
    ax0 /= an; ax1 /= an; ax2 /= an;
    float ayn = sqrtf(ay0 * ay0 + ay1 * ay1 + ay2 * ay2);
    ay0 /= ayn; ay1 /= ayn; ay2 /= ayn;
    float az0 = ax1 * ay2 - ax2 * ay1;
    float az1 = ax2 * ay0 - ax0 * ay2;
    float az2 = ax0 * ay1 - ax1 * ay0;
    svr[tid][0] = ax0; svr[tid][1] = ay0; svr[tid][2] = az0;
    svr[tid][3] = ax1; svr[tid][4] = ay1; svr[tid][5] = az1;
    svr[tid][6] = ax2; svr[tid][7] = ay2; svr[tid][8] = az2;
    if (b == 0) {
      float* m = views_rot_g + tid * 9;
#pragma unroll
      for (int i = 0; i < 9; i++) m[i] = svr[tid][i];
    }
  }
  __syncthreads();
  if (tid < NV) {
    float vx = sv[tid][0], vy = sv[tid][1], vz = sv[tid][2];
    float x = R[0] * vx + R[1] * vy + R[2] * vz;
    float y = R[3] * vx + R[4] * vy + R[5] * vz;
    float z = R[6] * vx + R[7] * vy + R[8] * vz;
    gv[tid][0] = x; gv[tid][1] = y; gv[tid][2] = z;
    gvr[tid] = x * x + y * y + z * z;
  }
  __syncthreads();
  if (tid < NV) {
    float qx = sv[tid][0], qy = sv[tid][1], qz = sv[tid][2];
    float qq = qx * qx + qy * qy + qz * qz;
    float best = INFINITY; int bi = 0;
    for (int u = 0; u < NV; u++) {
      float dot = qx * gv[u][0] + qy * gv[u][1] + qz * gv[u][2];
      float d = qq + gvr[u] - 2.f * dot;
      if (d < best) { best = d; bi = u; }
    }
    view_inds[b * NV + tid] = bi;
    const float* vr = svr[bi];
    float* o = Rsel + (b * NV + tid) * 9;
    for (int i = 0; i < 3; i++)
      for (int j = 0; j < 3; j++)
        o[i * 3 + j] = R[i * 3 + 0] * vr[0 + j] + R[i * 3 + 1] * vr[3 + j] + R[i * 3 + 2] * vr[6 + j];
  }
}

// ---------------------------------------------------------------- k_gcnt
// Streams grasp_labels ONCE, coalesced, deduped per grasp point (2000 rows
// per batch vs 4096 gathered rows). Stores g = cnt/48 per (b, p, view).
__global__ void __launch_bounds__(256) k_gcnt(const float* __restrict__ gscores,
                                              float* __restrict__ cntg) {
  int b = blockIdx.y, p = blockIdx.x, tid = threadIdx.x;
  const float* srow = gscores + ((size_t)(b * NGP + p)) * ROWLEN;
  float* crow = cntg + ((size_t)(b * NGP + p)) * NV;
  for (int u = tid; u < NV; u += 256) {
    const float4* q4 = (const float4*)(srow + u * 48);
    int cnt = 0;
#pragma unroll
    for (int q = 0; q < 12; q++) {
      float4 x = q4[q];
      cnt += (x.x > 0.f && x.x <= 0.6f);
      cnt += (x.y > 0.f && x.y <= 0.6f);
      cnt += (x.z > 0.f && x.z <= 0.6f);
      cnt += (x.w > 0.f && x.w <= 0.6f);
    }
    crow[u] = (float)cnt / 48.0f;
  }
}

// ---------------------------------------------------------------- k_nn
__global__ void __launch_bounds__(256) k_nn(
    const float* __restrict__ pc, const float* __restrict__ pose,
    const float* __restrict__ gpoints, int* __restrict__ nn_inds,
    float* __restrict__ out_gp) {
  int b = blockIdx.y;
  int s0 = blockIdx.x * 32;
  int tid = threadIdx.x;
  __shared__ float4 pts[NGP];          // 32 KB
  __shared__ float P[12];
  if (tid < 12) P[tid] = pose[b * 12 + tid];
  __syncthreads();
  for (int i = tid; i < NGP; i += 256) {
    float px = gpoints[((size_t)b * NGP + i) * 3 + 0];
    float py = gpoints[((size_t)b * NGP + i) * 3 + 1];
    float pz = gpoints[((size_t)b * NGP + i) * 3 + 2];
    float x = P[0] * px + P[1] * py + P[2] * pz + P[3];
    float y = P[4] * px + P[5] * py + P[6] * pz + P[7];
    float z = P[8] * px + P[9] * py + P[10] * pz + P[11];
    pts[i] = make_float4(x, y, z, x * x + y * y + z * z);
  }
  __syncthreads();
  int sl = tid & 31, chunk = tid >> 5;
  int s = s0 + sl;
  float qx = pc[((size_t)b * NSD + s) * 3 + 0];
  float qy = pc[((size_t)b * NSD + s) * 3 + 1];
  float qz = pc[((size_t)b * NSD + s) * 3 + 2];
  float qq = qx * qx + qy * qy + qz * qz;
  int i0 = chunk * 250;
  float best = INFINITY; int bi = i0;
  for (int i = i0; i < i0 + 250; i++) {
    float4 p = pts[i];
    float d = qq + p.w - 2.f * (qx * p.x + qy * p.y + qz * p.z);
    if (d < best) { best = d; bi = i; }
  }
  __shared__ float rb[8][33];
  __shared__ int ri[8][33];
  rb[chunk][sl] = best; ri[chunk][sl] = bi;
  __syncthreads();
  if (tid < 32) {
    float bb = INFINITY; int ii = 0;
    for (int c = 0; c < 8; c++) {          // ascending chunk order -> first-min ties
      float v = rb[c][tid];
      if (v < bb) { bb = v; ii = ri[c][tid]; }
    }
    nn_inds[b * NSD + s0 + tid] = ii;
    float4 p = pts[ii];
    out_gp[((size_t)b * NSD + s0 + tid) * 3 + 0] = p.x;
    out_gp[((size_t)b * NSD + s0 + tid) * 3 + 1] = p.y;
    out_gp[((size_t)b * NSD + s0 + tid) * 3 + 2] = p.z;
  }
}

// ---------------------------------------------------------------- gemm body
// 128x64 tile, BK=16, 256 threads, 8x4 micro-tile, double-buffered LDS:
// ONE barrier per K-step (was 2). Same FMA order as before -> bitwise-identical.
// fp32 on purpose: bf16/MFMA noise risks argmax flips (round-1 evidence).
__device__ __forceinline__ void gemm_body(
    const float* __restrict__ W, const float* __restrict__ Xb,
    const float* __restrict__ bias, float* __restrict__ Yb,
    int O, int Cin, int N, int m0, int n0, bool relu, bool guard,
    float (*As)[16][132], float (*Bs)[16][64]) {
  int tid = threadIdx.x;
  int mW = tid >> 1;             // 0..127
  int kW = (tid & 1) * 8;        // 0 or 8
  int kX = tid >> 4, nX = (tid & 15) * 4;
  int ty = tid >> 4, tx = tid & 15;  // micro: rows ty*8..+8, cols tx*4..+4
  bool okm = !guard || (m0 + mW) < O;
  float4 a0, a1, bv;
  {
    const float* wp = &W[(size_t)(m0 + mW) * Cin + kW];
    a0 = okm ? *(const float4*)wp : make_float4(0.f, 0.f, 0.f, 0.f);
    a1 = okm ? *(const float4*)(wp + 4) : make_float4(0.f, 0.f, 0.f, 0.f);
    bv = *(const float4*)&Xb[(size_t)kX * N + n0 + nX];
  }
  As[0][kW + 0][mW] = a0.x; As[0][kW + 1][mW] = a0.y;
  As[0][kW + 2][mW] = a0.z; As[0][kW + 3][mW] = a0.w;
  As[0][kW + 4][mW] = a1.x; As[0][kW + 5][mW] = a1.y;
  As[0][kW + 6][mW] = a1.z; As[0][kW + 7][mW] = a1.w;
  *(float4*)&Bs[0][kX][nX] = bv;
  __syncthreads();
  float acc[8][4] = {};
  int cur = 0;
  for (int k0 = 0; k0 < Cin; k0 += 16) {
    bool more = (k0 + 16) < Cin;
    if (more) {  // issue global prefetch before compute (overlaps FMAs)
      const float* wp = &W[(size_t)(m0 + mW) * Cin + k0 + 16 + kW];
      a0 = okm ? *(const float4*)wp : make_float4(0.f, 0.f, 0.f, 0.f);
      a1 = okm ? *(const float4*)(wp + 4) : make_float4(0.f, 0.f, 0.f, 0.f);
      bv = *(const float4*)&Xb[(size_t)(k0 + 16 + kX) * N + n0 + nX];
    }
#pragma unroll
    for (int kk = 0; kk < 16; kk++) {
      float4 x0 = *(const float4*)&As[cur][kk][ty * 8];
      float4 x1 = *(const float4*)&As[cur][kk][ty * 8 + 4];
      float4 y = *(const float4*)&Bs[cur][kk][tx * 4];
      acc[0][0] = fmaf(x0.x, y.x, acc[0][0]); acc[0][1] = fmaf(x0.x, y.y, acc[0][1]);
      acc[0][2] = fmaf(x0.x, y.z, acc[0][2]); acc[0][3] = fmaf(x0.x, y.w, acc[0][3]);
      acc[1][0] = fmaf(x0.y, y.x, acc[1][0]); acc[1][1] = fmaf(x0.y, y.y, acc[1][1]);
      acc[1][2] = fmaf(x0.y, y.z, acc[1][2]); acc[1][3] = fmaf(x0.y, y.w, acc[1][3]);
      acc[2][0] = fmaf(x0.z, y.x, acc[2][0]); acc[2][1] = fmaf(x0.z, y.y, acc[2][1]);
      acc[2][2] = fmaf(x0.z, y.z, acc[2][2]); acc[2][3] = fmaf(x0.z, y.w, acc[2][3]);
      acc[3][0] = fmaf(x0.w, y.x, acc[3][0]); acc[3][1] = fmaf(x0.w, y.y, acc[3][1]);
      acc[3][2] = fmaf(x0.w, y.z, acc[3][2]); acc[3][3] = fmaf(x0.w, y.w, acc[3][3]);
      acc[4][0] = fmaf(x1.x, y.x, acc[4][0]); acc[4][1] = fmaf(x1.x, y.y, acc[4][1]);
      acc[4][2] = fmaf(x1.x, y.z, acc[4][2]); acc[4][3] = fmaf(x1.x, y.w, acc[4][3]);
      acc[5][0] = fmaf(x1.y, y.x, acc[5][0]); acc[5][1] = fmaf(x1.y, y.y, acc[5][1]);
      acc[5][2] = fmaf(x1.y, y.z, acc[5][2]); acc[5][3] = fmaf(x1.y, y.w, acc[5][3]);
      acc[6][0] = fmaf(x1.z, y.x, acc[6][0]); acc[6][1] = fmaf(x1.z, y.y, acc[6][1]);
      acc[6][2] = fmaf(x1.z, y.z, acc[6][2]); acc[6][3] = fmaf(x1.z, y.w, acc[6][3]);
      acc[7][0] = fmaf(x1.w, y.x, acc[7][0]); acc[7][1] = fmaf(x1.w, y.y, acc[7][1]);
      acc[7][2] = fmaf(x1.w, y.z, acc[7][2]); acc[7][3] = fmaf(x1.w, y.w, acc[7][3]);
    }
    if (more) {  // write into the OTHER buffer; one barrier to publish
      int nxt = cur ^ 1;
      As[nxt][kW + 0][mW] = a0.x; As[nxt][kW + 1][mW] = a0.y;
      As[nxt][kW + 2][mW] = a0.z; As[nxt][kW + 3][mW] = a0.w;
      As[nxt][kW + 4][mW] = a1.x; As[nxt][kW + 5][mW] = a1.y;
      As[nxt][kW + 6][mW] = a1.z; As[nxt][kW + 7][mW] = a1.w;
      *(float4*)&Bs[nxt][kX][nX] = bv;
      __syncthreads();
      cur = nxt;
    }
  }
#pragma unroll
  for (int i = 0; i < 8; i++) {
    int m = m0 + ty * 8 + i;
    if (guard && m >= O) break;
    float bi = bias[m];
    float4 v;
    v.x = acc[i][0] + bi; v.y = acc[i][1] + bi;
    v.z = acc[i][2] + bi; v.w = acc[i][3] + bi;
    if (relu) {
      v.x = fmaxf(v.x, 0.f); v.y = fmaxf(v.y, 0.f);
      v.z = fmaxf(v.z, 0.f); v.w = fmaxf(v.w, 0.f);
    }
    *(float4*)&Yb[(size_t)m * N + n0 + (tx << 2)] = v;
  }
}

// ---------------------------------------------------------------- gemm128_db
template <bool RELU>
__global__ void __launch_bounds__(256) gemm128_db(
    const float* __restrict__ W, const float* __restrict__ X,
    const float* __restrict__ bias, float* __restrict__ Y,
    int O, int Cin, int N) {
  __shared__ float As[2][16][132];
  __shared__ float Bs[2][16][64];
  int b = blockIdx.z;
  gemm_body(W, X + (size_t)b * Cin * N, bias, Y + (size_t)b * O * N,
            O, Cin, N, blockIdx.y * 128, blockIdx.x * 64, RELU, false, As, Bs);
}

// ---------------------------------------------------------------- gemm_dual
// Fused sw1 (O=512, relu, m-tiles 0..3) + aw3 (O=300, no relu, m-tiles 4..6).
// Both read the same X (res2); 448 blocks = 1.75/CU vs two serial dispatches.
__global__ void __launch_bounds__(256) gemm_dual(
    const float* __restrict__ W1, const float* __restrict__ b1, float* __restrict__ Y1,
    const float* __restrict__ W2, const float* __restrict__ b2, float* __restrict__ Y2,
    const float* __restrict__ X) {
  __shared__ float As[2][16][132];
  __shared__ float Bs[2][16][64];
  int b = blockIdx.z;
  const float* Xb = X + (size_t)b * NC * NSD;
  if (blockIdx.y < 4) {
    gemm_body(W1, Xb, b1, Y1 + (size_t)b * NC * NSD, NC, NC, NSD,
              blockIdx.y * 128, blockIdx.x * 64, true, false, As, Bs);
  } else {
    gemm_body(W2, Xb, b2, Y2 + (size_t)b * NV * NSD, NV, NC, NSD,
              (blockIdx.y - 4) * 128, blockIdx.x * 64, false, true, As, Bs);
  }
}

// ---------------------------------------------------------------- gemm_sw2
__global__ void __launch_bounds__(256) gemm_sw2(
    const float* __restrict__ W, const float* __restrict__ X,
    const float* __restrict__ bias, float* __restrict__ gsp,
    float* __restrict__ gwp) {
  const int O = 96, Cin = NC, N = NSD;
  int b = blockIdx.z;
  const float* Xb = X + (size_t)b * Cin * N;
  int m0 = blockIdx.y * 64, n0 = blockIdx.x * 64;
  __shared__ float As[16][68];
  __shared__ float Bs[16][64];
  int tid = threadIdx.x;
  int mW = tid >> 2, kW = (tid & 3) * 4;
  int kX = tid >> 4, nX = (tid & 15) * 4;
  int ty = tid >> 4, tx = tid & 15;
  float acc[4][4] = {};
  for (int k0 = 0; k0 < Cin; k0 += 16) {
    float4 wv;
    if ((m0 + mW) < O)
      wv = *(const float4*)&W[(size_t)(m0 + mW) * Cin + k0 + kW];
    else
      wv = make_float4(0.f, 0.f, 0.f, 0.f);
    As[kW + 0][mW] = wv.x; As[kW + 1][mW] = wv.y;
    As[kW + 2][mW] = wv.z; As[kW + 3][mW] = wv.w;
    *(float4*)&Bs[kX][nX] = *(const float4*)&Xb[(size_t)(k0 + kX) * N + n0 + nX];
    __syncthreads();
#pragma unroll
    for (int kk = 0; kk < 16; kk++) {
      float4 a = *(const float4*)&As[kk][ty << 2];
      float4 bv = *(const float4*)&Bs[kk][tx << 2];
      acc[0][0] = fmaf(a.x, bv.x, acc[0][0]); acc[0][1] = fmaf(a.x, bv.y, acc[0][1]);
      acc[0][2] = fmaf(a.x, bv.z, acc[0][2]); acc[0][3] = fmaf(a.x, bv.w, acc[0][3]);
      acc[1][0] = fmaf(a.y, bv.x, acc[1][0]); acc[1][1] = fmaf(a.y, bv.y, acc[1][1]);
      acc[1][2] = fmaf(a.y, bv.z, acc[1][2]); acc[1][3] = fmaf(a.y, bv.w, acc[1][3]);
      acc[2][0] = fmaf(a.z, bv.x, acc[2][0]); acc[2][1] = fmaf(a.z, bv.y, acc[2][1]);
      acc[2][2] = fmaf(a.z, bv.z, acc[2][2]); acc[2][3] = fmaf(a.z, bv.w, acc[2][3]);
      acc[3][0] = fmaf(a.w, bv.x, acc[3][0]); acc[3][1] = fmaf(a.w, bv.y, acc[3][1]);
      acc[3][2] = fmaf(a.w, bv.z, acc[3][2]); acc[3][3] = fmaf(a.w, bv.w, acc[3][3]);
    }
    __syncthreads();
  }
  int m = m0 + ty * 4;
  if (m < O) {
    float b0 = bias[m], b1 = bias[m + 1], b2 = bias[m + 2], b3 = bias[m + 3];
#pragma unroll
    for (int j = 0; j < 4; j++) {
      int n = n0 + (tx << 2) + j;
      float4 v;
      v.x = acc[0][j] + b0; v.y = acc[1][j] + b1;
      v.z = acc[2][j] + b2; v.w = acc[3][j] + b3;
      size_t base = ((size_t)b * NSD + n) * 48;
      if (m < 48) *(float4*)&gsp[base + m] = v;
      else        *(float4*)&gwp[base + m - 48] = v;
    }
  }
}

// ---------------------------------------------------------------- k_view
__global__ void __launch_bounds__(256) k_view(
    const float* __restrict__ vs_t, const float* __restrict__ views_rot,
    const float* __restrict__ Rsel, int* __restrict__ tv_inds,
    float* __restrict__ o_vs, float* __restrict__ o_vprot,
    float* __restrict__ o_trot) {
  int b = blockIdx.y, n0 = blockIdx.x * 32;
  int tx = threadIdx.x, ty = threadIdx.y;
  __shared__ float tile[32][33];
  __shared__ float bval[8][32];
  __shared__ int bidx[8][32];
  const float* src = vs_t + (size_t)b * NV * NSD;
  float best = -INFINITY; int bi = 0;
  for (int v0 = 0; v0 < NV; v0 += 32) {
    int vlim = (NV - v0 < 32) ? (NV - v0) : 32;
    for (int i = ty; i < vlim; i += 8)
      tile[i][tx] = src[(size_t)(v0 + i) * NSD + n0 + tx];
    __syncthreads();
    if (v0 + tx < NV) {                 // transposed write: v = v0+tx
#pragma unroll
      for (int j = 0; j < 4; j++) {
        int nl = ty * 4 + j;
        o_vs[((size_t)b * NSD + n0 + nl) * NV + v0 + tx] = tile[tx][nl];
      }
    }
    for (int i = ty; i < vlim; i += 8) {  // argmax partial: n = n0+tx
      float val = tile[i][tx];
      if (val > best) { best = val; bi = v0 + i; }
    }
    __syncthreads();
  }
  bval[ty][tx] = best; bidx[ty][tx] = bi;
  __syncthreads();
  if (ty == 0) {
    for (int t = 1; t < 8; t++) {
      float v = bval[t][tx]; int ii = bidx[t][tx];
      if (v > best || (v == best && ii < bi)) { best = v; bi = ii; }
    }
    int n = n0 + tx;
    tv_inds[b * NSD + n] = bi;
    const float* vr = views_rot + bi * 9;
    const float* rs = Rsel + (b * NV + bi) * 9;
    float* o1 = o_vprot + ((size_t)b * NSD + n) * 9;
    float* o4 = o_trot + ((size_t)b * NSD + n) * 9;
#pragma unroll
    for (int i = 0; i < 9; i++) { o1[i] = vr[i]; o4[i] = rs[i]; }
  }
}

// ---------------------------------------------------------------- k_grasp2
// Light per-seed pass: gather precomputed g (L2-hot), normalize, plus the
// 48-wide raw/twd gathers. One wave per block; max/min exact (order-free).
__global__ void __launch_bounds__(64) k_grasp2(
    const float* __restrict__ cntg, const float* __restrict__ gscores,
    const float* __restrict__ goffsets, const int* __restrict__ nn_inds,
    const int* __restrict__ tv_inds, const int* __restrict__ view_inds,
    float* __restrict__ o_grsp, float* __restrict__ o_twd,
    float* __restrict__ raw) {
  int b = blockIdx.y, s = blockIdx.x, lane = threadIdx.x;
  int nn = nn_inds[b * NSD + s];
  int tv = tv_inds[b * NSD + s];
  int vit = view_inds[b * NV + tv];
  const float* srow = gscores + ((size_t)(b * NGP + nn)) * ROWLEN;
  const float* wrow = goffsets + ((size_t)(b * NGP + nn)) * ROWLEN;
  if (lane < 48) {
    float sc = srow[vit * 48 + lane];
    float wd = wrow[vit * 48 + lane];
    bool m = (sc > 0.f) && (wd <= 0.1f);
    o_twd[((size_t)b * NSD + s) * 48 + lane] = wd;
    raw[((size_t)b * NSD + s) * 48 + lane] = m ? sc : 0.f;
  }
  const float* crow = cntg + ((size_t)(b * NGP + nn)) * NV;
  const int* vib = view_inds + b * NV;
  float g[5];
  float mx = -INFINITY, mn = INFINITY;
#pragma unroll
  for (int i = 0; i < 5; i++) {
    int v = lane + i * 64;
    if (v < NV) {
      float val = crow[vib[v]];
      g[i] = val;
      mx = fmaxf(mx, val); mn = fminf(mn, val);
    }
  }
#pragma unroll
  for (int off = 32; off; off >>= 1) {
    mx = fmaxf(mx, __shfl_down(mx, off));
    mn = fminf(mn, __shfl_down(mn, off));
  }
  mx = __shfl(mx, 0); mn = __shfl(mn, 0);
  float denom = mx - mn + 1e-8f;
  float* og = o_grsp + ((size_t)b * NSD + s) * NV;
#pragma unroll
  for (int i = 0; i < 5; i++) {
    int v = lane + i * 64;
    if (v < NV) og[v] = (g[i] - mn) / denom;
  }
}

// ---------------------------------------------------------------- k_reduce
__global__ void __launch_bounds__(256) k_reduce(const float* __restrict__ raw,
                                                int n, int* __restrict__ mmx) {
  float mx = -INFINITY, mn = INFINITY;
  for (int i = blockIdx.x * 256 + threadIdx.x; i < n; i += gridDim.x * 256) {
    float v = raw[i];
    mx = fmaxf(mx, v);
    if (v > 0.f) mn = fminf(mn, v);
  }
  for (int off = 32; off; off >>= 1) {
    mx = fmaxf(mx, __shfl_down(mx, off));
    mn = fminf(mn, __shfl_down(mn, off));
  }
  __shared__ float smx[4], smn[4];
  int wid = threadIdx.x >> 6, lane = threadIdx.x & 63;
  if (lane == 0) { smx[wid] = mx; smn[wid] = mn; }
  __syncthreads();
  if (threadIdx.x == 0) {
    mx = fmaxf(fmaxf(smx[0], smx[1]), fmaxf(smx[2], smx[3]));
    mn = fminf(fminf(smn[0], smn[1]), fminf(smn[2], smn[3]));
    atomicMax(&mmx[0], __float_as_int(mx));   // values >= 0: int order == float order
    if (mn != INFINITY) atomicMin(&mmx[1], __float_as_int(mn));
  }
}

// ---------------------------------------------------------------- k_topsc
__global__ void k_topsc(const float* __restrict__ raw, const int* __restrict__ mmx,
                        float* __restrict__ out, int n) {
  int i = blockIdx.x * 256 + threadIdx.x;
  if (i >= n) return;
  float sc = raw[i];
  float umax = __int_as_float(mmx[0]);
  float umin = __int_as_float(mmx[1]);
  float denom = logf(umax / umin) + 1e-8f;
  float val = logf(umax / sc) / denom;
  out[i] = (sc > 0.f) ? val : sc;
}

// ================================================================ launch
extern "C" void kernel_launch(void* const* d_in, const int* in_sizes, int n_in,
                              void* d_out, int out_size, void* d_ws, size_t ws_size,
                              hipStream_t stream) {
  const float* seed_features = (const float*)d_in[0];
  const float* point_clouds  = (const float*)d_in[1];
  const float* object_pose   = (const float*)d_in[2];
  const float* grasp_points  = (const float*)d_in[3];
  const float* grasp_labels  = (const float*)d_in[4];
  const float* grasp_offsets = (const float*)d_in[5];
  const float* aw1_w = (const float*)d_in[6];
  const float* aw1_b = (const float*)d_in[7];
  const float* aw2_w = (const float*)d_in[8];
  const float* aw2_b = (const float*)d_in[9];
  const float* aw3_w = (const float*)d_in[10];
  const float* aw3_b = (const float*)d_in[11];
  const float* sw1_w = (const float*)d_in[12];
  const float* sw1_b = (const float*)d_in[13];
  const float* sw2_w = (const float*)d_in[14];
  const float* sw2_b = (const float*)d_in[15];

  float* out = (float*)d_out;
  float* o_vs    = out;                      // (B,NS,300)
  float* o_vprot = o_vs + NB * NSD * NV;     // (B,NS,3,3)
  float* o_gsp   = o_vprot + NB * NSD * 9;   // (B,NS,12,4)
  float* o_gwp   = o_gsp + NB * NSD * 48;
  float* o_trot  = o_gwp + NB * NSD * 48;    // (B,NS,3,3)
  float* o_tsc   = o_trot + NB * NSD * 9;
  float* o_twd   = o_tsc + NB * NSD * 48;
  float* o_grsp  = o_twd + NB * NSD * 48;    // (B,NS,300)
  float* o_gp    = o_grsp + NB * NSD * NV;   // (B,NS,3)

  float* w = (float*)d_ws;
  float* res1 = w; w += NB * NC * NSD;       // aw1 out, reused as sw1 out
  float* res2 = w; w += NB * NC * NSD;
  float* vs_t = w; w += NB * NV * NSD;
  float* cntg = w; w += NB * NGP * NV;       // 4.8 MB precomputed graspness
  float* views_rot = w; w += 2720;
  float* Rsel = w; w += NB * NV * 9;
  float* raw  = w; w += NB * NSD * 48;
  int* view_inds = (int*)w; w += NB * NV;
  int* nn_inds   = (int*)w; w += NB * NSD;
  int* tv_inds   = (int*)w; w += NB * NSD;
  int* mmx       = (int*)w; w += 8;

  k_setup_all<<<NB, 512, 0, stream>>>(object_pose, views_rot, view_inds, Rsel, mmx);
  k_gcnt<<<dim3(NGP, NB), 256, 0, stream>>>(grasp_labels, cntg);
  k_nn<<<dim3(NSD / 32, NB), 256, 0, stream>>>(point_clouds, object_pose, grasp_points,
                                               nn_inds, o_gp);

  gemm128_db<true><<<dim3(NSD / 64, NC / 128, NB), 256, 0, stream>>>(
      aw1_w, seed_features, aw1_b, res1, NC, NC, NSD);
  gemm128_db<true><<<dim3(NSD / 64, NC / 128, NB), 256, 0, stream>>>(
      aw2_w, res1, aw2_b, res2, NC, NC, NSD);
  gemm_dual<<<dim3(NSD / 64, 7, NB), 256, 0, stream>>>(
      sw1_w, sw1_b, res1, aw3_w, aw3_b, vs_t, res2);
  gemm_sw2<<<dim3(NSD / 64, 2, NB), 256, 0, stream>>>(sw2_w, res1, sw2_b, o_gsp, o_gwp);

  k_view<<<dim3(NSD / 32, NB), dim3(32, 8), 0, stream>>>(
      vs_t, views_rot, Rsel, tv_inds, o_vs, o_vprot, o_trot);
  k_grasp2<<<dim3(NSD, NB), 64, 0, stream>>>(cntg, grasp_labels, grasp_offsets,
                                             nn_inds, tv_inds, view_inds,
                                             o_grsp, o_twd, raw);
  k_reduce<<<256, 256, 0, stream>>>(raw, NB * NSD * 48, mmx);
  k_topsc<<<(NB * NSD * 48 + 255) / 256, 256, 0, stream>>>(raw, mmx, o_tsc, NB * NSD * 48);
}

// Round 4
// 626.772 us; speedup vs baseline: 1.0436x; 1.0436x over previous
//
#include <hip/hip_runtime.h>
#include <math.h>
#include <stdint.h>

#define NV 300
#define NA 12
#define ND 4
#define NB 2
#define NC 512
#define NSD 2048
#define NGP 2000
#define ROWLEN 14400  // NV*NA*ND

// ---------------------------------------------------------------- k_setup_all
__global__ void __launch_bounds__(512) k_setup_all(
    const float* __restrict__ pose, float* __restrict__ views_rot_g,
    int* __restrict__ view_inds, float* __restrict__ Rsel, int* __restrict__ mmx) {
  int b = blockIdx.x, tid = threadIdx.x;
  __shared__ float sv[NV][3];
  __shared__ float svr[NV][9];
  __shared__ float R[9];
  __shared__ float gv[NV][3];
  __shared__ float gvr[NV];
  if (b == 0 && tid == 0) { mmx[0] = 0; mmx[1] = 0x7f800000; }  // umax=0, umin=+inf
  if (tid < 9) R[tid] = pose[b * 12 + (tid / 3) * 4 + (tid % 3)];
  if (tid < NV) {
    float fi = (float)tid;
    float Z = (2.0f * fi + 1.0f) / 300.0f - 1.0f;
    float r = sqrtf(fmaxf(1.0f - Z * Z, 0.0f));
    float ang = (6.28318530717958647692f * fi) * 0.61803398874989484820f;
    float X = r * cosf(ang);
    float Y = r * sinf(ang);
    sv[tid][0] = X; sv[tid][1] = Y; sv[tid][2] = Z;
    float ax0 = -X, ax1 = -Y, ax2 = -Z;
    float ay0 = -ax1, ay1 = ax0, ay2 = 0.f;      // from UNNORMALIZED ax
    float ynorm = sqrtf(ay0 * ay0 + ay1 * ay1 + ay2 * ay2);
    if (ynorm == 0.f) { ay0 = 0.f; ay1 = 1.f; ay2 = 0.f; }
    float an = sqrtf(ax0 * ax0 + ax1 * ax1 + ax2 * ax2);
    ax0 /= an; ax1 /= an; ax2 /= an;
    float ayn = sqrtf(ay0 * ay0 + ay1 * ay1 + ay2 * ay2);
    ay0 /= ayn; ay1 /= ayn; ay2 /= ayn;
    float az0 = ax1 * ay2 - ax2 * ay1;
    float az1 = ax2 * ay0 - ax0 * ay2;
    float az2 = ax0 * ay1 - ax1 * ay0;
    svr[tid][0] = ax0; svr[tid][1] = ay0; svr[tid][2] = az0;
    svr[tid][3] = ax1; svr[tid][4] = ay1; svr[tid][5] = az1;
    svr[tid][6] = ax2; svr[tid][7] = ay2; svr[tid][8] = az2;
    if (b == 0) {
      float* m = views_rot_g + tid * 9;
#pragma unroll
      for (int i = 0; i < 9; i++) m[i] = svr[tid][i];
    }
  }
  __syncthreads();
  if (tid < NV) {
    float vx = sv[tid][0], vy = sv[tid][1], vz = sv[tid][2];
    float x = R[0] * vx + R[1] * vy + R[2] * vz;
    float y = R[3] * vx + R[4] * vy + R[5] * vz;
    float z = R[6] * vx + R[7] * vy + R[8] * vz;
    gv[tid][0] = x; gv[tid][1] = y; gv[tid][2] = z;
    gvr[tid] = x * x + y * y + z * z;
  }
  __syncthreads();
  if (tid < NV) {
    float qx = sv[tid][0], qy = sv[tid][1], qz = sv[tid][2];
    float qq = qx * qx + qy * qy + qz * qz;
    float best = INFINITY; int bi = 0;
    for (int u = 0; u < NV; u++) {
      float dot = qx * gv[u][0] + qy * gv[u][1] + qz * gv[u][2];
      float d = qq + gvr[u] - 2.f * dot;
      if (d < best) { best = d; bi = u; }
    }
    view_inds[b * NV + tid] = bi;
    const float* vr = svr[bi];
    float* o = Rsel + (b * NV + tid) * 9;
    for (int i = 0; i < 3; i++)
      for (int j = 0; j < 3; j++)
        o[i * 3 + j] = R[i * 3 + 0] * vr[0 + j] + R[i * 3 + 1] * vr[3 + j] + R[i * 3 + 2] * vr[6 + j];
  }
}

// ---------------------------------------------------------------- k_nn
__global__ void __launch_bounds__(256) k_nn(
    const float* __restrict__ pc, const float* __restrict__ pose,
    const float* __restrict__ gpoints, int* __restrict__ nn_inds,
    float* __restrict__ out_gp) {
  int b = blockIdx.y;
  int s0 = blockIdx.x * 32;
  int tid = threadIdx.x;
  __shared__ float4 pts[NGP];          // 32 KB
  __shared__ float P[12];
  if (tid < 12) P[tid] = pose[b * 12 + tid];
  __syncthreads();
  for (int i = tid; i < NGP; i += 256) {
    float px = gpoints[((size_t)b * NGP + i) * 3 + 0];
    float py = gpoints[((size_t)b * NGP + i) * 3 + 1];
    float pz = gpoints[((size_t)b * NGP + i) * 3 + 2];
    float x = P[0] * px + P[1] * py + P[2] * pz + P[3];
    float y = P[4] * px + P[5] * py + P[6] * pz + P[7];
    float z = P[8] * px + P[9] * py + P[10] * pz + P[11];
    pts[i] = make_float4(x, y, z, x * x + y * y + z * z);
  }
  __syncthreads();
  int sl = tid & 31, chunk = tid >> 5;
  int s = s0 + sl;
  float qx = pc[((size_t)b * NSD + s) * 3 + 0];
  float qy = pc[((size_t)b * NSD + s) * 3 + 1];
  float qz = pc[((size_t)b * NSD + s) * 3 + 2];
  float qq = qx * qx + qy * qy + qz * qz;
  int i0 = chunk * 250;
  float best = INFINITY; int bi = i0;
  for (int i = i0; i < i0 + 250; i++) {
    float4 p = pts[i];
    float d = qq + p.w - 2.f * (qx * p.x + qy * p.y + qz * p.z);
    if (d < best) { best = d; bi = i; }
  }
  __shared__ float rb[8][33];
  __shared__ int ri[8][33];
  rb[chunk][sl] = best; ri[chunk][sl] = bi;
  __syncthreads();
  if (tid < 32) {
    float bb = INFINITY; int ii = 0;
    for (int c = 0; c < 8; c++) {          // ascending chunk order -> first-min ties
      float v = rb[c][tid];
      if (v < bb) { bb = v; ii = ri[c][tid]; }
    }
    nn_inds[b * NSD + s0 + tid] = ii;
    float4 p = pts[ii];
    out_gp[((size_t)b * NSD + s0 + tid) * 3 + 0] = p.x;
    out_gp[((size_t)b * NSD + s0 + tid) * 3 + 1] = p.y;
    out_gp[((size_t)b * NSD + s0 + tid) * 3 + 2] = p.z;
  }
}

// ---------------------------------------------------------------- gemm128_sk
// 128x64 tile, 512 threads = 2 wave-groups; group g accumulates K-half g
// (in-block split-K2). Fixes the 1-wave/SIMD latency exposure of the 256-thread
// version: 2 waves/SIMD + half the barrier drains per group. Group 1 publishes
// partials via LDS; group 0 combines (acc0 + p1) + bias in fixed order ->
// deterministic. fp32 on purpose (bf16/MFMA argmax-flip risk, round-1 evidence).
template <bool RELU, bool GUARD_M>
__global__ void __launch_bounds__(512) gemm128_sk(
    const float* __restrict__ W, const float* __restrict__ X,
    const float* __restrict__ bias, float* __restrict__ Y,
    int O, int Cin, int N) {
  int b = blockIdx.z;
  const float* Xb = X + (size_t)b * Cin * N;
  float* Yb = Y + (size_t)b * O * N;
  int m0 = blockIdx.y * 128, n0 = blockIdx.x * 64;
  __shared__ float As[2][16][132];  // [group][k][m], padded
  __shared__ float Bs[2][16][64];   // [group][k][n]
  __shared__ float Ps[128][68];     // partial exchange (group1 -> group0)
  int tid = threadIdx.x & 255;
  int grp = threadIdx.x >> 8;       // 0 or 1
  int KH = Cin >> 1;
  int kbase = grp * KH;
  int mW = tid >> 1;                // 0..127
  int kW = (tid & 1) * 8;           // 0 or 8
  int kX = tid >> 4, nX = (tid & 15) * 4;
  int ty = tid >> 4, tx = tid & 15; // micro: rows ty*8..+8, cols tx*4..+4
  bool okm = !GUARD_M || (m0 + mW) < O;
  float4 a0, a1, bv;
  {
    const float* wp = &W[(size_t)(m0 + mW) * Cin + kbase + kW];
    a0 = okm ? *(const float4*)wp : make_float4(0.f, 0.f, 0.f, 0.f);
    a1 = okm ? *(const float4*)(wp + 4) : make_float4(0.f, 0.f, 0.f, 0.f);
    bv = *(const float4*)&Xb[(size_t)(kbase + kX) * N + n0 + nX];
  }
  float acc[8][4] = {};
  for (int k0 = 0; k0 < KH; k0 += 16) {
    __syncthreads();
    As[grp][kW + 0][mW] = a0.x; As[grp][kW + 1][mW] = a0.y;
    As[grp][kW + 2][mW] = a0.z; As[grp][kW + 3][mW] = a0.w;
    As[grp][kW + 4][mW] = a1.x; As[grp][kW + 5][mW] = a1.y;
    As[grp][kW + 6][mW] = a1.z; As[grp][kW + 7][mW] = a1.w;
    *(float4*)&Bs[grp][kX][nX] = bv;
    __syncthreads();
    if (k0 + 16 < KH) {   // register prefetch of next K-slab (overlaps FMAs)
      const float* wp = &W[(size_t)(m0 + mW) * Cin + kbase + k0 + 16 + kW];
      a0 = okm ? *(const float4*)wp : make_float4(0.f, 0.f, 0.f, 0.f);
      a1 = okm ? *(const float4*)(wp + 4) : make_float4(0.f, 0.f, 0.f, 0.f);
      bv = *(const float4*)&Xb[(size_t)(kbase + k0 + 16 + kX) * N + n0 + nX];
    }
#pragma unroll
    for (int kk = 0; kk < 16; kk++) {
      float4 x0 = *(const float4*)&As[grp][kk][ty * 8];
      float4 x1 = *(const float4*)&As[grp][kk][ty * 8 + 4];
      float4 y = *(const float4*)&Bs[grp][kk][tx * 4];
      acc[0][0] = fmaf(x0.x, y.x, acc[0][0]); acc[0][1] = fmaf(x0.x, y.y, acc[0][1]);
      acc[0][2] = fmaf(x0.x, y.z, acc[0][2]); acc[0][3] = fmaf(x0.x, y.w, acc[0][3]);
      acc[1][0] = fmaf(x0.y, y.x, acc[1][0]); acc[1][1] = fmaf(x0.y, y.y, acc[1][1]);
      acc[1][2] = fmaf(x0.y, y.z, acc[1][2]); acc[1][3] = fmaf(x0.y, y.w, acc[1][3]);
      acc[2][0] = fmaf(x0.z, y.x, acc[2][0]); acc[2][1] = fmaf(x0.z, y.y, acc[2][1]);
      acc[2][2] = fmaf(x0.z, y.z, acc[2][2]); acc[2][3] = fmaf(x0.z, y.w, acc[2][3]);
      acc[3][0] = fmaf(x0.w, y.x, acc[3][0]); acc[3][1] = fmaf(x0.w, y.y, acc[3][1]);
      acc[3][2] = fmaf(x0.w, y.z, acc[3][2]); acc[3][3] = fmaf(x0.w, y.w, acc[3][3]);
      acc[4][0] = fmaf(x1.x, y.x, acc[4][0]); acc[4][1] = fmaf(x1.x, y.y, acc[4][1]);
      acc[4][2] = fmaf(x1.x, y.z, acc[4][2]); acc[4][3] = fmaf(x1.x, y.w, acc[4][3]);
      acc[5][0] = fmaf(x1.y, y.x, acc[5][0]); acc[5][1] = fmaf(x1.y, y.y, acc[5][1]);
      acc[5][2] = fmaf(x1.y, y.z, acc[5][2]); acc[5][3] = fmaf(x1.y, y.w, acc[5][3]);
      acc[6][0] = fmaf(x1.z, y.x, acc[6][0]); acc[6][1] = fmaf(x1.z, y.y, acc[6][1]);
      acc[6][2] = fmaf(x1.z, y.z, acc[6][2]); acc[6][3] = fmaf(x1.z, y.w, acc[6][3]);
      acc[7][0] = fmaf(x1.w, y.x, acc[7][0]); acc[7][1] = fmaf(x1.w, y.y, acc[7][1]);
      acc[7][2] = fmaf(x1.w, y.z, acc[7][2]); acc[7][3] = fmaf(x1.w, y.w, acc[7][3]);
    }
  }
  // combine: group 1 publishes partials, group 0 adds + bias + relu + store
  if (grp == 1) {
#pragma unroll
    for (int i = 0; i < 8; i++)
      *(float4*)&Ps[ty * 8 + i][tx * 4] =
          make_float4(acc[i][0], acc[i][1], acc[i][2], acc[i][3]);
  }
  __syncthreads();
  if (grp == 0) {
#pragma unroll
    for (int i = 0; i < 8; i++) {
      int m = m0 + ty * 8 + i;
      if (GUARD_M && m >= O) break;
      float bi = bias[m];
      float4 p = *(const float4*)&Ps[ty * 8 + i][tx * 4];
      float4 v;
      v.x = (acc[i][0] + p.x) + bi; v.y = (acc[i][1] + p.y) + bi;
      v.z = (acc[i][2] + p.z) + bi; v.w = (acc[i][3] + p.w) + bi;
      if (RELU) {
        v.x = fmaxf(v.x, 0.f); v.y = fmaxf(v.y, 0.f);
        v.z = fmaxf(v.z, 0.f); v.w = fmaxf(v.w, 0.f);
      }
      *(float4*)&Yb[(size_t)m * N + n0 + (tx << 2)] = v;
    }
  }
}

// ---------------------------------------------------------------- gemm_sw2
// sw2 GEMM (O=96) with fused split epilogue: writes gsp/gwp in (B,NS,12,4)
// layout directly.
__global__ void __launch_bounds__(256) gemm_sw2(
    const float* __restrict__ W, const float* __restrict__ X,
    const float* __restrict__ bias, float* __restrict__ gsp,
    float* __restrict__ gwp) {
  const int O = 96, Cin = NC, N = NSD;
  int b = blockIdx.z;
  const float* Xb = X + (size_t)b * Cin * N;
  int m0 = blockIdx.y * 64, n0 = blockIdx.x * 64;
  __shared__ float As[16][68];
  __shared__ float Bs[16][64];
  int tid = threadIdx.x;
  int mW = tid >> 2, kW = (tid & 3) * 4;
  int kX = tid >> 4, nX = (tid & 15) * 4;
  int ty = tid >> 4, tx = tid & 15;
  float acc[4][4] = {};
  for (int k0 = 0; k0 < Cin; k0 += 16) {
    float4 wv;
    if ((m0 + mW) < O)
      wv = *(const float4*)&W[(size_t)(m0 + mW) * Cin + k0 + kW];
    else
      wv = make_float4(0.f, 0.f, 0.f, 0.f);
    As[kW + 0][mW] = wv.x; As[kW + 1][mW] = wv.y;
    As[kW + 2][mW] = wv.z; As[kW + 3][mW] = wv.w;
    *(float4*)&Bs[kX][nX] = *(const float4*)&Xb[(size_t)(k0 + kX) * N + n0 + nX];
    __syncthreads();
#pragma unroll
    for (int kk = 0; kk < 16; kk++) {
      float4 a = *(const float4*)&As[kk][ty << 2];
      float4 bv = *(const float4*)&Bs[kk][tx << 2];
      acc[0][0] = fmaf(a.x, bv.x, acc[0][0]); acc[0][1] = fmaf(a.x, bv.y, acc[0][1]);
      acc[0][2] = fmaf(a.x, bv.z, acc[0][2]); acc[0][3] = fmaf(a.x, bv.w, acc[0][3]);
      acc[1][0] = fmaf(a.y, bv.x, acc[1][0]); acc[1][1] = fmaf(a.y, bv.y, acc[1][1]);
      acc[1][2] = fmaf(a.y, bv.z, acc[1][2]); acc[1][3] = fmaf(a.y, bv.w, acc[1][3]);
      acc[2][0] = fmaf(a.z, bv.x, acc[2][0]); acc[2][1] = fmaf(a.z, bv.y, acc[2][1]);
      acc[2][2] = fmaf(a.z, bv.z, acc[2][2]); acc[2][3] = fmaf(a.z, bv.w, acc[2][3]);
      acc[3][0] = fmaf(a.w, bv.x, acc[3][0]); acc[3][1] = fmaf(a.w, bv.y, acc[3][1]);
      acc[3][2] = fmaf(a.w, bv.z, acc[3][2]); acc[3][3] = fmaf(a.w, bv.w, acc[3][3]);
    }
    __syncthreads();
  }
  int m = m0 + ty * 4;
  if (m < O) {
    float b0 = bias[m], b1 = bias[m + 1], b2 = bias[m + 2], b3 = bias[m + 3];
#pragma unroll
    for (int j = 0; j < 4; j++) {
      int n = n0 + (tx << 2) + j;
      float4 v;
      v.x = acc[0][j] + b0; v.y = acc[1][j] + b1;
      v.z = acc[2][j] + b2; v.w = acc[3][j] + b3;
      size_t base = ((size_t)b * NSD + n) * 48;
      if (m < 48) *(float4*)&gsp[base + m] = v;
      else        *(float4*)&gwp[base + m - 48] = v;
    }
  }
}

// ---------------------------------------------------------------- k_view
__global__ void __launch_bounds__(256) k_view(
    const float* __restrict__ vs_t, const float* __restrict__ views_rot,
    const float* __restrict__ Rsel, int* __restrict__ tv_inds,
    float* __restrict__ o_vs, float* __restrict__ o_vprot,
    float* __restrict__ o_trot) {
  int b = blockIdx.y, n0 = blockIdx.x * 32;
  int tx = threadIdx.x, ty = threadIdx.y;
  __shared__ float tile[32][33];
  __shared__ float bval[8][32];
  __shared__ int bidx[8][32];
  const float* src = vs_t + (size_t)b * NV * NSD;
  float best = -INFINITY; int bi = 0;
  for (int v0 = 0; v0 < NV; v0 += 32) {
    int vlim = (NV - v0 < 32) ? (NV - v0) : 32;
    for (int i = ty; i < vlim; i += 8)
      tile[i][tx] = src[(size_t)(v0 + i) * NSD + n0 + tx];
    __syncthreads();
    if (v0 + tx < NV) {                 // transposed write: v = v0+tx
#pragma unroll
      for (int j = 0; j < 4; j++) {
        int nl = ty * 4 + j;
        o_vs[((size_t)b * NSD + n0 + nl) * NV + v0 + tx] = tile[tx][nl];
      }
    }
    for (int i = ty; i < vlim; i += 8) {  // argmax partial: n = n0+tx
      float val = tile[i][tx];
      if (val > best) { best = val; bi = v0 + i; }
    }
    __syncthreads();
  }
  bval[ty][tx] = best; bidx[ty][tx] = bi;
  __syncthreads();
  if (ty == 0) {
    for (int t = 1; t < 8; t++) {
      float v = bval[t][tx]; int ii = bidx[t][tx];
      if (v > best || (v == best && ii < bi)) { best = v; bi = ii; }
    }
    int n = n0 + tx;
    tv_inds[b * NSD + n] = bi;
    const float* vr = views_rot + bi * 9;
    const float* rs = Rsel + (b * NV + bi) * 9;
    float* o1 = o_vprot + ((size_t)b * NSD + n) * 9;
    float* o4 = o_trot + ((size_t)b * NSD + n) * 9;
#pragma unroll
    for (int i = 0; i < 9; i++) { o1[i] = vr[i]; o4[i] = rs[i]; }
  }
}

// ---------------------------------------------------------------- k_grasp
__global__ void __launch_bounds__(256) k_grasp(
    const float* __restrict__ gscores, const float* __restrict__ goffsets,
    const int* __restrict__ nn_inds, const int* __restrict__ tv_inds,
    const int* __restrict__ view_inds, float* __restrict__ o_grsp,
    float* __restrict__ o_twd, float* __restrict__ raw) {
  int b = blockIdx.y, s = blockIdx.x, tid = threadIdx.x;
  __shared__ int vi[NV];
  for (int v = tid; v < NV; v += 256) vi[v] = view_inds[b * NV + v];
  __syncthreads();
  int nn = nn_inds[b * NSD + s];
  int tv = tv_inds[b * NSD + s];
  int vit = vi[tv];
  const float* srow = gscores + ((size_t)(b * NGP + nn)) * ROWLEN;
  const float* wrow = goffsets + ((size_t)(b * NGP + nn)) * ROWLEN;
  if (tid < 48) {
    float sc = srow[vit * 48 + tid];
    float wd = wrow[vit * 48 + tid];
    bool m = (sc > 0.f) && (wd <= 0.1f);
    o_twd[((size_t)b * NSD + s) * 48 + tid] = wd;
    raw[((size_t)b * NSD + s) * 48 + tid] = m ? sc : 0.f;
  }
  __shared__ float g[NV];
  for (int v = tid; v < NV; v += 256) {
    int vv = vi[v];
    const float4* p = (const float4*)(srow + vv * 48);
    int cnt = 0;
#pragma unroll
    for (int q = 0; q < 12; q++) {
      float4 x = p[q];
      cnt += (x.x > 0.f && x.x <= 0.6f);
      cnt += (x.y > 0.f && x.y <= 0.6f);
      cnt += (x.z > 0.f && x.z <= 0.6f);
      cnt += (x.w > 0.f && x.w <= 0.6f);
    }
    g[v] = (float)cnt / 48.0f;
  }
  __syncthreads();
  float mx = -INFINITY, mn = INFINITY;
  for (int v = tid; v < NV; v += 256) { mx = fmaxf(mx, g[v]); mn = fminf(mn, g[v]); }
  for (int off = 32; off; off >>= 1) {
    mx = fmaxf(mx, __shfl_down(mx, off));
    mn = fminf(mn, __shfl_down(mn, off));
  }
  __shared__ float wmx[4], wmn[4];
  int wid = tid >> 6, lane = tid & 63;
  if (lane == 0) { wmx[wid] = mx; wmn[wid] = mn; }
  __syncthreads();
  if (tid == 0) {
    mx = fmaxf(fmaxf(wmx[0], wmx[1]), fmaxf(wmx[2], wmx[3]));
    mn = fminf(fminf(wmn[0], wmn[1]), fminf(wmn[2], wmn[3]));
    wmx[0] = mx; wmn[0] = mn;
  }
  __syncthreads();
  mx = wmx[0]; mn = wmn[0];
  float denom = mx - mn + 1e-8f;
  float* og = o_grsp + ((size_t)b * NSD + s) * NV;
  for (int v = tid; v < NV; v += 256) og[v] = (g[v] - mn) / denom;
}

// ---------------------------------------------------------------- k_reduce
__global__ void __launch_bounds__(256) k_reduce(const float* __restrict__ raw,
                                                int n, int* __restrict__ mmx) {
  float mx = -INFINITY, mn = INFINITY;
  for (int i = blockIdx.x * 256 + threadIdx.x; i < n; i += gridDim.x * 256) {
    float v = raw[i];
    mx = fmaxf(mx, v);
    if (v > 0.f) mn = fminf(mn, v);
  }
  for (int off = 32; off; off >>= 1) {
    mx = fmaxf(mx, __shfl_down(mx, off));
    mn = fminf(mn, __shfl_down(mn, off));
  }
  __shared__ float smx[4], smn[4];
  int wid = threadIdx.x >> 6, lane = threadIdx.x & 63;
  if (lane == 0) { smx[wid] = mx; smn[wid] = mn; }
  __syncthreads();
  if (threadIdx.x == 0) {
    mx = fmaxf(fmaxf(smx[0], smx[1]), fmaxf(smx[2], smx[3]));
    mn = fminf(fminf(smn[0], smn[1]), fminf(smn[2], smn[3]));
    atomicMax(&mmx[0], __float_as_int(mx));   // values >= 0: int order == float order
    if (mn != INFINITY) atomicMin(&mmx[1], __float_as_int(mn));
  }
}

// ---------------------------------------------------------------- k_topsc
__global__ void k_topsc(const float* __restrict__ raw, const int* __restrict__ mmx,
                        float* __restrict__ out, int n) {
  int i = blockIdx.x * 256 + threadIdx.x;
  if (i >= n) return;
  float sc = raw[i];
  float umax = __int_as_float(mmx[0]);
  float umin = __int_as_float(mmx[1]);
  float denom = logf(umax / umin) + 1e-8f;
  float val = logf(umax / sc) / denom;
  out[i] = (sc > 0.f) ? val : sc;
}

// ================================================================ launch
extern "C" void kernel_launch(void* const* d_in, const int* in_sizes, int n_in,
                              void* d_out, int out_size, void* d_ws, size_t ws_size,
                              hipStream_t stream) {
  const float* seed_features = (const float*)d_in[0];
  const float* point_clouds  = (const float*)d_in[1];
  const float* object_pose   = (const float*)d_in[2];
  const float* grasp_points  = (const float*)d_in[3];
  const float* grasp_labels  = (const float*)d_in[4];
  const float* grasp_offsets = (const float*)d_in[5];
  const float* aw1_w = (const float*)d_in[6];
  const float* aw1_b = (const float*)d_in[7];
  const float* aw2_w = (const float*)d_in[8];
  const float* aw2_b = (const float*)d_in[9];
  const float* aw3_w = (const float*)d_in[10];
  const float* aw3_b = (const float*)d_in[11];
  const float* sw1_w = (const float*)d_in[12];
  const float* sw1_b = (const float*)d_in[13];
  const float* sw2_w = (const float*)d_in[14];
  const float* sw2_b = (const float*)d_in[15];

  float* out = (float*)d_out;
  float* o_vs    = out;                      // (B,NS,300)
  float* o_vprot = o_vs + NB * NSD * NV;     // (B,NS,3,3)
  float* o_gsp   = o_vprot + NB * NSD * 9;   // (B,NS,12,4)
  float* o_gwp   = o_gsp + NB * NSD * 48;
  float* o_trot  = o_gwp + NB * NSD * 48;    // (B,NS,3,3)
  float* o_tsc   = o_trot + NB * NSD * 9;
  float* o_twd   = o_tsc + NB * NSD * 48;
  float* o_grsp  = o_twd + NB * NSD * 48;    // (B,NS,300)
  float* o_gp    = o_grsp + NB * NSD * NV;   // (B,NS,3)

  float* w = (float*)d_ws;
  float* res1 = w; w += NB * NC * NSD;       // aw1 out, reused as sw1 out
  float* res2 = w; w += NB * NC * NSD;
  float* vs_t = w; w += NB * NV * NSD;
  float* views_rot = w; w += 2720;
  float* Rsel = w; w += NB * NV * 9;
  float* raw  = w; w += NB * NSD * 48;
  int* view_inds = (int*)w; w += NB * NV;
  int* nn_inds   = (int*)w; w += NB * NSD;
  int* tv_inds   = (int*)w; w += NB * NSD;
  int* mmx       = (int*)w; w += 8;

  k_setup_all<<<NB, 512, 0, stream>>>(object_pose, views_rot, view_inds, Rsel, mmx);
  k_nn<<<dim3(NSD / 32, NB), 256, 0, stream>>>(point_clouds, object_pose, grasp_points,
                                               nn_inds, o_gp);

  gemm128_sk<true, false><<<dim3(NSD / 64, NC / 128, NB), 512, 0, stream>>>(
      aw1_w, seed_features, aw1_b, res1, NC, NC, NSD);
  gemm128_sk<true, false><<<dim3(NSD / 64, NC / 128, NB), 512, 0, stream>>>(
      aw2_w, res1, aw2_b, res2, NC, NC, NSD);
  gemm128_sk<false, true><<<dim3(NSD / 64, (NV + 127) / 128, NB), 512, 0, stream>>>(
      aw3_w, res2, aw3_b, vs_t, NV, NC, NSD);
  gemm128_sk<true, false><<<dim3(NSD / 64, NC / 128, NB), 512, 0, stream>>>(
      sw1_w, res2, sw1_b, res1, NC, NC, NSD);
  gemm_sw2<<<dim3(NSD / 64, 2, NB), 256, 0, stream>>>(sw2_w, res1, sw2_b, o_gsp, o_gwp);

  k_view<<<dim3(NSD / 32, NB), dim3(32, 8), 0, stream>>>(
      vs_t, views_rot, Rsel, tv_inds, o_vs, o_vprot, o_trot);
  k_grasp<<<dim3(NSD, NB), 256, 0, stream>>>(grasp_labels, grasp_offsets, nn_inds,
                                             tv_inds, view_inds, o_grsp, o_twd, raw);
  k_reduce<<<256, 256, 0, stream>>>(raw, NB * NSD * 48, mmx);
  k_topsc<<<(NB * NSD * 48 + 255) / 256, 256, 0, stream>>>(raw, mmx, o_tsc, NB * NSD * 48);
}